// Round 2
// baseline (1802.842 us; speedup 1.0000x reference)
//
#include <hip/hip_runtime.h>

#define NNODES 50000
#define NEDGES 400000
#define NMOLS  2000

// ---- ws layout (floats) ----
constexpr size_t OFF_NF1 = 0;            // 50000*54 accumulators (zeroed)
constexpr size_t OFF_NF2 = 2700000;      // 50000*27 (zeroed)
constexpr size_t OFF_NF3 = 4050000;      // 50000    (zeroed)
constexpr size_t OFF_DEG = 4100000;      // 50000    (zeroed)
constexpr size_t ZERO_FLOATS = 4150000;  // end of zeroed region
constexpr size_t OFF_EATTR = 4150000;    // 400000*9
constexpr size_t OFF_G   = 7750000;      // 50000*26
constexpr size_t OFF_T   = 9050000;      // 50000*136
constexpr size_t OFF_HH  = 15850000;     // 50000*9
constexpr size_t OFF_DIS = 16300000;     // 50000
// total 16350000 floats = 65.4 MB

__device__ __forceinline__ void atomAdd(float* p, float v) {
  unsafeAtomicAdd(p, v);
}

// node: first = relu(x@lin_w^T + lin_b); g = TP1 per-node precompute (26)
__global__ void k_node1(const float* __restrict__ x, const float* __restrict__ lw,
                        const float* __restrict__ lb, const float* __restrict__ w1,
                        float* __restrict__ g) {
  int n = blockIdx.x * blockDim.x + threadIdx.x;
  if (n >= NNODES) return;
  float f[23];
  const float* xr = x + n * 23;
  #pragma unroll
  for (int v = 0; v < 23; ++v) {
    float acc = lb[v];
    const float* wr = lw + v * 23;
    #pragma unroll
    for (int c = 0; c < 23; ++c) acc += xr[c] * wr[c];
    f[v] = fmaxf(acc, 0.f);
  }
  float* gn = g + n * 26;
  #pragma unroll
  for (int w = 0; w < 16; ++w) { float a = 0; for (int v = 0; v < 23; ++v) a += f[v] * w1[v * 16 + w]; gn[w] = a; }
  #pragma unroll
  for (int w = 0; w < 6;  ++w) { float a = 0; for (int v = 0; v < 23; ++v) a += f[v] * w1[368 + v * 6 + w]; gn[16 + w] = a; }
  #pragma unroll
  for (int w = 0; w < 4;  ++w) { float a = 0; for (int v = 0; v < 23; ++v) a += f[v] * w1[506 + v * 4 + w]; gn[22 + w] = a; }
}

// edge: sh/eattr, deg, TP1 combine -> scatter nf1acc[dst] (54)
__global__ void k_edge1(const float* __restrict__ pos, const float* __restrict__ ea,
                        const int* __restrict__ src, const int* __restrict__ dst,
                        const float* __restrict__ g,
                        float* __restrict__ eattr, float* __restrict__ nf1acc,
                        float* __restrict__ deg) {
  int e = blockIdx.x * blockDim.x + threadIdx.x;
  if (e >= NEDGES) return;
  int s = src[e], d = dst[e];
  float xx = pos[s * 3 + 0] - pos[d * 3 + 0];
  float yy = pos[s * 3 + 1] - pos[d * 3 + 1];
  float zz = pos[s * 3 + 2] - pos[d * 3 + 2];
  float r2 = xx * xx + yy * yy + zz * zz;
  const float s3 = 1.7320508075688772f, s5c = 2.2360679774997896f, s15 = 3.872983346207417f;
  float w0 = ea[e * 7];
  float et[9];
  et[0] = w0;
  et[1] = w0 * s3 * yy;
  et[2] = w0 * s3 * zz;
  et[3] = w0 * s3 * xx;
  et[4] = w0 * s15 * xx * yy;
  et[5] = w0 * s15 * yy * zz;
  et[6] = w0 * 0.5f * s5c * (3.f * zz * zz - r2);
  et[7] = w0 * s15 * xx * zz;
  et[8] = w0 * 0.5f * s15 * (xx * xx - yy * yy);
  float* eo = eattr + e * 9;
  #pragma unroll
  for (int q = 0; q < 9; ++q) eo[q] = et[q];
  atomAdd(deg + d, 1.f);
  const float S23 = 0.20851441405707477f; // 1/sqrt(23)
  const float* gs = g + s * 26;
  float* acc = nf1acc + d * 54;
  float c0 = S23 * et[0];
  #pragma unroll
  for (int w = 0; w < 16; ++w) atomAdd(acc + w, c0 * gs[w]);
  #pragma unroll
  for (int k = 0; k < 3; ++k) {
    float c = S23 * et[1 + k];
    #pragma unroll
    for (int u = 0; u < 6; ++u) atomAdd(acc + 16 + u * 3 + k, c * gs[16 + u]);
  }
  #pragma unroll
  for (int K = 0; K < 5; ++K) {
    float c = S23 * et[4 + K];
    #pragma unroll
    for (int u = 0; u < 4; ++u) atomAdd(acc + 34 + u * 5 + K, c * gs[22 + u]);
  }
}

// node: dis = rsqrt(deg); nf1 = nf1acc*dis; TP2 per-node precompute t (136)
__global__ void k_node2(const float* __restrict__ nf1acc, const float* __restrict__ deg,
                        const float* __restrict__ w2, float* __restrict__ t,
                        float* __restrict__ dis) {
  int n = blockIdx.x * blockDim.x + threadIdx.x;
  if (n >= NNODES) return;
  float di = rsqrtf(deg[n]);
  dis[n] = di;
  float A[54];
  const float* a = nf1acc + n * 54;
  #pragma unroll
  for (int i = 0; i < 54; ++i) A[i] = a[i] * di;
  float* tn = t + n * 136;
  // from A0 (l=0, 16)
  #pragma unroll
  for (int w = 0; w < 8; ++w) { float s = 0; for (int u = 0; u < 16; ++u) s += A[u] * w2[u * 8 + w]; tn[w] = s; }
  #pragma unroll
  for (int w = 0; w < 3; ++w) { float s = 0; for (int u = 0; u < 16; ++u) s += A[u] * w2[128 + u * 3 + w]; tn[8 + w] = s; }
  #pragma unroll
  for (int w = 0; w < 2; ++w) { float s = 0; for (int u = 0; u < 16; ++u) s += A[u] * w2[176 + u * 2 + w]; tn[11 + w] = s; }
  // from A1 (l=1, 6 muls x 3): A[16+u*3+k]
  #pragma unroll
  for (int w = 0; w < 3; ++w) for (int k = 0; k < 3; ++k) { float s = 0; for (int u = 0; u < 6; ++u) s += A[16 + u * 3 + k] * w2[298 + u * 3 + w]; tn[13 + w * 3 + k] = s; }
  #pragma unroll
  for (int w = 0; w < 8; ++w) for (int j = 0; j < 3; ++j) { float s = 0; for (int u = 0; u < 6; ++u) s += A[16 + u * 3 + j] * w2[316 + u * 8 + w]; tn[22 + w * 3 + j] = s; }
  #pragma unroll
  for (int w = 0; w < 2; ++w) for (int i = 0; i < 3; ++i) { float s = 0; for (int u = 0; u < 6; ++u) s += A[16 + u * 3 + i] * w2[382 + u * 2 + w]; tn[46 + w * 3 + i] = s; }
  #pragma unroll
  for (int w = 0; w < 3; ++w) for (int i = 0; i < 3; ++i) { float s = 0; for (int u = 0; u < 6; ++u) s += A[16 + u * 3 + i] * w2[394 + u * 3 + w]; tn[52 + w * 3 + i] = s; }
  // from A2 (l=2, 4 muls x 5): A[34+u*5+K]
  #pragma unroll
  for (int w = 0; w < 2; ++w) for (int K = 0; K < 5; ++K) { float s = 0; for (int u = 0; u < 4; ++u) s += A[34 + u * 5 + K] * w2[436 + u * 2 + w]; tn[61 + w * 5 + K] = s; }
  #pragma unroll
  for (int w = 0; w < 3; ++w) for (int I = 0; I < 5; ++I) { float s = 0; for (int u = 0; u < 4; ++u) s += A[34 + u * 5 + I] * w2[444 + u * 3 + w]; tn[71 + w * 5 + I] = s; }
  #pragma unroll
  for (int w = 0; w < 8; ++w) for (int J = 0; J < 5; ++J) { float s = 0; for (int u = 0; u < 4; ++u) s += A[34 + u * 5 + J] * w2[472 + u * 8 + w]; tn[86 + w * 5 + J] = s; }
  #pragma unroll
  for (int w = 0; w < 2; ++w) for (int I = 0; I < 5; ++I) { float s = 0; for (int u = 0; u < 4; ++u) s += A[34 + u * 5 + I] * w2[516 + u * 2 + w]; tn[126 + w * 5 + I] = s; }
}

// edge: TP2 combine (live paths only) -> scatter nf2acc[dst] (27)
__global__ void k_edge2(const float* __restrict__ eattr, const int* __restrict__ src,
                        const int* __restrict__ dst, const float* __restrict__ t,
                        float* __restrict__ nf2acc) {
  int e = blockIdx.x * blockDim.x + threadIdx.x;
  if (e >= NEDGES) return;
  int s = src[e], d = dst[e];
  const float* et = eattr + e * 9;
  float b0 = et[0];
  float b1[3] = { et[1], et[2], et[3] };
  float b2[5] = { et[4], et[5], et[6], et[7], et[8] };
  const float* tn = t + s * 136;
  const float S26 = 0.19611613513818404f; // sqrt(1/26)
  const float S14 = 0.2672612419124244f;  // sqrt(1/14)
  const float S8  = 0.35355339059327373f; // sqrt(1/8)
  const float I3  = 0.5773502691896258f;  // 1/sqrt(3)
  const float I5  = 0.4472135954999579f;  // 1/sqrt(5)
  const float CA = 0.18257418583505536f;  // 1/sqrt(30)
  const float CB = 0.31622776601683794f;  // 1/sqrt(10)
  const float CC = 0.3651483716701107f;   // 2/sqrt(30)
  const float SG = 1.f; // sigma for w3j(2,2,2): +Gaunt (round-1 evidence: -1 gave 1.87x refmax error)
  const float P = SG * 0.2390457218668787f;
  const float Q = SG * 0.2070196678027063f;
  const float R = SG * 0.1195228609334394f;

  float cb112[3][5] = {
    {  CB * b1[2],  CB * b1[1], -CA * b1[0], 0.f,        -CB * b1[0] },
    {  0.f,         CB * b1[0],  CC * b1[1], CB * b1[2],  0.f        },
    {  CB * b1[0],  0.f,        -CA * b1[2], CB * b1[1],  CB * b1[2] }
  };
  float cb121[3][3] = {
    { -CA * b2[2] - CB * b2[4], CB * b2[1], CB * b2[0] },
    {  CB * b2[1],              CC * b2[2], CB * b2[3] },
    {  CB * b2[0],              CB * b2[3], -CA * b2[2] + CB * b2[4] }
  };
  float cb211[5][3] = {
    {  CB * b1[2], 0.f,        CB * b1[0] },
    {  CB * b1[1], CB * b1[0], 0.f        },
    { -CA * b1[0], CC * b1[1], -CA * b1[2] },
    {  0.f,        CB * b1[2], CB * b1[1] },
    { -CB * b1[0], 0.f,        CB * b1[2] }
  };
  float cb222[5][5] = {
    { -P * b2[2],  Q * b2[3],              -P * b2[0],  Q * b2[1],               0.f       },
    {  Q * b2[3],  R * b2[2] - Q * b2[4],   R * b2[1],  Q * b2[0],              -Q * b2[1] },
    { -P * b2[0],  R * b2[1],               P * b2[2],  R * b2[3],              -P * b2[4] },
    {  Q * b2[1],  Q * b2[0],               R * b2[3],  R * b2[2] + Q * b2[4],   Q * b2[3] },
    {  0.f,       -Q * b2[1],              -P * b2[4],  Q * b2[3],              -P * b2[2] }
  };

  float* acc = nf2acc + d * 27;
  // O0 (8 scalars): paths (0,0,0), (2,1,0), (3,2,0)
  #pragma unroll
  for (int w = 0; w < 8; ++w) {
    float s5j = 0;
    #pragma unroll
    for (int j = 0; j < 3; ++j) s5j += tn[22 + w * 3 + j] * b1[j];
    float s10 = 0;
    #pragma unroll
    for (int J = 0; J < 5; ++J) s10 += tn[86 + w * 5 + J] * b2[J];
    atomAdd(acc + w, S26 * (b0 * tn[w] + I3 * s5j + I5 * s10));
  }
  // O2 (3x3): paths (0,1,2), (2,0,2), (2,2,2), (3,1,2)
  #pragma unroll
  for (int w = 0; w < 3; ++w) {
    #pragma unroll
    for (int k = 0; k < 3; ++k) {
      float v = I3 * (b1[k] * tn[8 + w] + b0 * tn[13 + w * 3 + k]);
      #pragma unroll
      for (int i = 0; i < 3; ++i) v += tn[52 + w * 3 + i] * cb121[i][k];
      #pragma unroll
      for (int I = 0; I < 5; ++I) v += tn[71 + w * 5 + I] * cb211[I][k];
      atomAdd(acc + 8 + w * 3 + k, S14 * v);
    }
  }
  // O3 (2x5): paths (0,2,3), (3,0,3), (2,1,3), (3,2,3)
  #pragma unroll
  for (int w = 0; w < 2; ++w) {
    #pragma unroll
    for (int K = 0; K < 5; ++K) {
      float v = I5 * (b2[K] * tn[11 + w] + b0 * tn[61 + w * 5 + K]);
      #pragma unroll
      for (int i = 0; i < 3; ++i) v += tn[46 + w * 3 + i] * cb112[i][K];
      #pragma unroll
      for (int I = 0; I < 5; ++I) v += tn[126 + w * 5 + I] * cb222[I][K];
      atomAdd(acc + 17 + w * 5 + K, S8 * v);
    }
  }
}

// node: nf2 = nf2acc*dis; TP3 per-node precompute hh (9)
__global__ void k_node3(const float* __restrict__ nf2acc, const float* __restrict__ dis,
                        const float* __restrict__ w3, float* __restrict__ hh) {
  int n = blockIdx.x * blockDim.x + threadIdx.x;
  if (n >= NNODES) return;
  float di = dis[n];
  const float* a = nf2acc + n * 27;
  const float S13 = 0.2773500981126146f; // sqrt(1/13)
  const float I3 = 0.5773502691896258f, I5 = 0.4472135954999579f;
  float t3a = 0;
  #pragma unroll
  for (int u = 0; u < 8; ++u) t3a += a[u] * w3[u];
  float* h = hh + n * 9;
  h[0] = S13 * t3a * di;
  #pragma unroll
  for (int j = 0; j < 3; ++j) {
    float s = 0;
    #pragma unroll
    for (int u = 0; u < 3; ++u) s += a[8 + u * 3 + j] * w3[8 + u];
    h[1 + j] = S13 * I3 * s * di;
  }
  #pragma unroll
  for (int K = 0; K < 5; ++K) {
    float s = 0;
    #pragma unroll
    for (int u = 0; u < 2; ++u) s += a[17 + u * 5 + K] * w3[11 + u];
    h[4 + K] = S13 * I5 * s * di;
  }
}

// edge: TP3 = dot9(hh[src], eattr) -> scatter nf3acc[dst]
__global__ void k_edge3(const float* __restrict__ eattr, const int* __restrict__ src,
                        const int* __restrict__ dst, const float* __restrict__ hh,
                        float* __restrict__ nf3acc) {
  int e = blockIdx.x * blockDim.x + threadIdx.x;
  if (e >= NEDGES) return;
  int s = src[e], d = dst[e];
  const float* et = eattr + e * 9;
  const float* h = hh + s * 9;
  float v = 0;
  #pragma unroll
  for (int q = 0; q < 9; ++q) v += h[q] * et[q];
  atomAdd(nf3acc + d, v);
}

// node -> molecule: out[mol] += nf3acc[n]*dis[n] / 5   (apm == 25 exactly)
__global__ void k_node4(const float* __restrict__ nf3acc, const float* __restrict__ dis,
                        const int* __restrict__ batch, float* __restrict__ out) {
  int n = blockIdx.x * blockDim.x + threadIdx.x;
  if (n >= NNODES) return;
  atomAdd(out + batch[n], nf3acc[n] * dis[n] * 0.2f);
}

extern "C" void kernel_launch(void* const* d_in, const int* in_sizes, int n_in,
                              void* d_out, int out_size, void* d_ws, size_t ws_size,
                              hipStream_t stream) {
  const float* positions = (const float*)d_in[0];
  const float* x         = (const float*)d_in[1];
  const float* edge_attr = (const float*)d_in[2];
  const float* lin_w     = (const float*)d_in[3];
  const float* lin_b     = (const float*)d_in[4];
  const float* w_tp1     = (const float*)d_in[5];
  const float* w_tp2     = (const float*)d_in[6];
  const float* w_tp3     = (const float*)d_in[7];
  const int*   edge_src  = (const int*)d_in[8];
  const int*   edge_dst  = (const int*)d_in[9];
  const int*   batch     = (const int*)d_in[10];
  float* out = (float*)d_out;
  float* ws = (float*)d_ws;

  float* nf1acc = ws + OFF_NF1;
  float* nf2acc = ws + OFF_NF2;
  float* nf3acc = ws + OFF_NF3;
  float* deg    = ws + OFF_DEG;
  float* eattr  = ws + OFF_EATTR;
  float* g      = ws + OFF_G;
  float* t      = ws + OFF_T;
  float* hh     = ws + OFF_HH;
  float* dis    = ws + OFF_DIS;

  hipMemsetAsync(ws, 0, ZERO_FLOATS * sizeof(float), stream);
  hipMemsetAsync(out, 0, (size_t)out_size * sizeof(float), stream);

  const int BN = 256;
  dim3 nodeGrid((NNODES + BN - 1) / BN), edgeGrid((NEDGES + BN - 1) / BN), blk(BN);

  k_node1<<<nodeGrid, blk, 0, stream>>>(x, lin_w, lin_b, w_tp1, g);
  k_edge1<<<edgeGrid, blk, 0, stream>>>(positions, edge_attr, edge_src, edge_dst, g,
                                        eattr, nf1acc, deg);
  k_node2<<<nodeGrid, blk, 0, stream>>>(nf1acc, deg, w_tp2, t, dis);
  k_edge2<<<edgeGrid, blk, 0, stream>>>(eattr, edge_src, edge_dst, t, nf2acc);
  k_node3<<<nodeGrid, blk, 0, stream>>>(nf2acc, dis, w_tp3, hh);
  k_edge3<<<edgeGrid, blk, 0, stream>>>(eattr, edge_src, edge_dst, hh, nf3acc);
  k_node4<<<nodeGrid, blk, 0, stream>>>(nf3acc, dis, batch, out);
}

// Round 3
// 642.883 us; speedup vs baseline: 2.8043x; 2.8043x over previous
//
#include <hip/hip_runtime.h>

#define NNODES 50000
#define NEDGES 400000
#define NMOLS  2000
#define NBLK   196   // ceil(NNODES/256)

// ---- ws layout (4-byte units) ----
constexpr size_t OFF_CNT   = 0;         // 50000 int (zeroed each call)
constexpr size_t OFF_OFFS  = 50000;     // 50000 int
constexpr size_t OFF_CURS  = 100000;    // 50000 int
constexpr size_t OFF_BSUM  = 150000;    // 256 int
constexpr size_t OFF_PAIRS = 150256;    // 400000 int2 (even offset -> 8B aligned)
constexpr size_t OFF_G     = 950256;    // 50000*28 floats (26 used, pad, 16B-aligned rows)
constexpr size_t OFF_NF1   = 2350256;   // 50000*56 floats (54 used)
constexpr size_t OFF_HH    = 5150256;   // 50000*12 floats (9 used)
// total 5750256 * 4B = 23 MB

__device__ __forceinline__ void make_b(float w0, float dx, float dy, float dz, float* b) {
  const float s3 = 1.7320508075688772f, s5c = 2.2360679774997896f, s15 = 3.872983346207417f;
  float r2 = dx * dx + dy * dy + dz * dz;
  b[0] = w0;
  b[1] = w0 * s3 * dy;
  b[2] = w0 * s3 * dz;
  b[3] = w0 * s3 * dx;
  b[4] = w0 * s15 * dx * dy;
  b[5] = w0 * s15 * dy * dz;
  b[6] = w0 * 0.5f * s5c * (3.f * dz * dz - r2);
  b[7] = w0 * s15 * dx * dz;
  b[8] = w0 * 0.5f * s15 * (dx * dx - dy * dy);
}

// ---------- CSR build ----------
__global__ void k_count(const int* __restrict__ dst, int* __restrict__ cnt) {
  int e = blockIdx.x * blockDim.x + threadIdx.x;
  if (e < NEDGES) atomicAdd(cnt + dst[e], 1);
}

__global__ void k_scanA(const int* __restrict__ cnt, int* __restrict__ offs, int* __restrict__ bsum) {
  __shared__ int sh[256];
  int t = threadIdx.x, i = blockIdx.x * 256 + t;
  int c = (i < NNODES) ? cnt[i] : 0;
  sh[t] = c; __syncthreads();
  #pragma unroll
  for (int off = 1; off < 256; off <<= 1) {
    int v = (t >= off) ? sh[t - off] : 0; __syncthreads();
    sh[t] += v; __syncthreads();
  }
  if (i < NNODES) offs[i] = sh[t] - c;          // exclusive within block
  if (t == 255) bsum[blockIdx.x] = sh[255];     // block total
}

__global__ void k_scanB(int* __restrict__ bsum) {
  __shared__ int sh[256];
  int t = threadIdx.x;
  int v = (t < NBLK) ? bsum[t] : 0;
  sh[t] = v; __syncthreads();
  #pragma unroll
  for (int off = 1; off < 256; off <<= 1) {
    int u = (t >= off) ? sh[t - off] : 0; __syncthreads();
    sh[t] += u; __syncthreads();
  }
  bsum[t] = sh[t] - v;                          // exclusive across blocks
}

__global__ void k_scanC(int* __restrict__ offs, int* __restrict__ curs, const int* __restrict__ bsum) {
  int i = blockIdx.x * 256 + threadIdx.x;
  if (i < NNODES) {
    int o = offs[i] + bsum[blockIdx.x];
    offs[i] = o;
    curs[i] = o;
  }
}

__global__ void k_fill(const int* __restrict__ src, const int* __restrict__ dst,
                       int* __restrict__ curs, int2* __restrict__ pairs) {
  int e = blockIdx.x * blockDim.x + threadIdx.x;
  if (e < NEDGES) {
    int d = dst[e];
    int pos = atomicAdd(curs + d, 1);
    pairs[pos] = make_int2(e, src[e]);
  }
}

// ---------- node linear + TP1 precompute ----------
__global__ void k_node1(const float* __restrict__ x, const float* __restrict__ lw,
                        const float* __restrict__ lb, const float* __restrict__ w1,
                        float* __restrict__ g) {
  int n = blockIdx.x * blockDim.x + threadIdx.x;
  if (n >= NNODES) return;
  float f[23];
  const float* xr = x + (size_t)n * 23;
  #pragma unroll
  for (int v = 0; v < 23; ++v) {
    float acc = lb[v];
    const float* wr = lw + v * 23;
    #pragma unroll
    for (int c = 0; c < 23; ++c) acc += xr[c] * wr[c];
    f[v] = fmaxf(acc, 0.f);
  }
  float* gn = g + (size_t)n * 28;
  #pragma unroll
  for (int w = 0; w < 16; ++w) { float a = 0; for (int v = 0; v < 23; ++v) a += f[v] * w1[v * 16 + w]; gn[w] = a; }
  #pragma unroll
  for (int w = 0; w < 6;  ++w) { float a = 0; for (int v = 0; v < 23; ++v) a += f[v] * w1[368 + v * 6 + w]; gn[16 + w] = a; }
  #pragma unroll
  for (int w = 0; w < 4;  ++w) { float a = 0; for (int v = 0; v < 23; ++v) a += f[v] * w1[506 + v * 4 + w]; gn[22 + w] = a; }
}

// ---------- layer 1 gather: nf1[d] = S23 * dis[d] * sum_e b(e) (x) g[src] ----------
__global__ void __launch_bounds__(64, 1)
k_gather1(const float* __restrict__ pos, const float* __restrict__ ea,
          const int* __restrict__ offs, const int* __restrict__ cnt,
          const int2* __restrict__ pairs, const float* __restrict__ g,
          float* __restrict__ nf1) {
  int n = blockIdx.x * blockDim.x + threadIdx.x;
  if (n >= NNODES) return;
  int beg = offs[n], cn = cnt[n];
  float pdx = pos[3 * n], pdy = pos[3 * n + 1], pdz = pos[3 * n + 2];
  float M[54];
  #pragma unroll
  for (int i = 0; i < 54; ++i) M[i] = 0.f;
  for (int j = 0; j < cn; ++j) {
    int2 pr = pairs[beg + j];
    int e = pr.x, s = pr.y;
    float w0 = ea[(size_t)e * 7];
    float dx = pos[3 * s] - pdx, dy = pos[3 * s + 1] - pdy, dz = pos[3 * s + 2] - pdz;
    float b[9]; make_b(w0, dx, dy, dz, b);
    float G[28];
    const float4* Gf = (const float4*)(g + (size_t)s * 28);
    #pragma unroll
    for (int q = 0; q < 7; ++q) { float4 v = Gf[q]; G[4*q]=v.x; G[4*q+1]=v.y; G[4*q+2]=v.z; G[4*q+3]=v.w; }
    #pragma unroll
    for (int u = 0; u < 16; ++u) M[u] += b[0] * G[u];
    #pragma unroll
    for (int u = 0; u < 6; ++u)
      #pragma unroll
      for (int k = 0; k < 3; ++k) M[16 + 3 * u + k] += b[1 + k] * G[16 + u];
    #pragma unroll
    for (int u = 0; u < 4; ++u)
      #pragma unroll
      for (int K = 0; K < 5; ++K) M[34 + 5 * u + K] += b[4 + K] * G[22 + u];
  }
  const float S23 = 0.20851441405707477f; // 1/sqrt(23)
  float sc = S23 * rsqrtf((float)cn);
  float* o = nf1 + (size_t)n * 56;
  #pragma unroll
  for (int i = 0; i < 54; ++i) o[i] = sc * M[i];
}

// ---------- layer 2 gather: full TP2 on edge from nf1[src]; writes hh[d][9] ----------
__global__ void __launch_bounds__(64, 1)
k_gather2(const float* __restrict__ pos, const float* __restrict__ ea,
          const int* __restrict__ offs, const int* __restrict__ cnt,
          const int2* __restrict__ pairs, const float* __restrict__ nf1,
          const float* __restrict__ w2, const float* __restrict__ w3,
          float* __restrict__ hh) {
  __shared__ float W[596];
  for (int i = threadIdx.x; i < 596; i += blockDim.x) W[i] = w2[i];
  __syncthreads();
  int n = blockIdx.x * blockDim.x + threadIdx.x;
  if (n >= NNODES) return;
  int beg = offs[n], cn = cnt[n];
  float pdx = pos[3 * n], pdy = pos[3 * n + 1], pdz = pos[3 * n + 2];
  float O0[8], O2[9], O3[10];
  #pragma unroll
  for (int i = 0; i < 8; ++i) O0[i] = 0.f;
  #pragma unroll
  for (int i = 0; i < 9; ++i) O2[i] = 0.f;
  #pragma unroll
  for (int i = 0; i < 10; ++i) O3[i] = 0.f;

  const float I3 = 0.5773502691896258f, I5 = 0.4472135954999579f;
  const float CA = 0.18257418583505536f, CB = 0.31622776601683794f, CC = 0.3651483716701107f;
  const float P = 0.2390457218668787f, Q = 0.2070196678027063f, R = 0.1195228609334394f;

  for (int j = 0; j < cn; ++j) {
    int2 pr = pairs[beg + j];
    int e = pr.x, s = pr.y;
    float w0 = ea[(size_t)e * 7];
    float dx = pos[3 * s] - pdx, dy = pos[3 * s + 1] - pdy, dz = pos[3 * s + 2] - pdz;
    float b[9]; make_b(w0, dx, dy, dz, b);
    float A[56];
    const float4* Af = (const float4*)(nf1 + (size_t)s * 56);
    #pragma unroll
    for (int q = 0; q < 14; ++q) { float4 v = Af[q]; A[4*q]=v.x; A[4*q+1]=v.y; A[4*q+2]=v.z; A[4*q+3]=v.w; }

    // per-edge CG-weighted b products
    float CBb1_0 = CB * b[1], CBb1_1 = CB * b[2], CBb1_2 = CB * b[3];
    float CAb1_0 = CA * b[1], CAb1_2 = CA * b[3], CCb1_1 = CC * b[2];
    float c121_00 = -CA * b[6] - CB * b[8], c121_01 = CB * b[5], c121_02 = CB * b[4];
    float c121_11 = CC * b[6], c121_12 = CB * b[7], c121_22 = -CA * b[6] + CB * b[8];
    float Pb2_0 = P * b[4], Pb2_2 = P * b[6], Pb2_4 = P * b[8];
    float Qb2_0 = Q * b[4], Qb2_1 = Q * b[5], Qb2_3 = Q * b[7], Qb2_4 = Q * b[8];
    float Rb2_1 = R * b[5], Rb2_2 = R * b[6], Rb2_3 = R * b[7];

    // ---- O0 (8): paths (0,0,0), (2,1,0), (3,2,0) ----
    #pragma unroll
    for (int w = 0; w < 8; ++w) {
      float t0 = 0;
      #pragma unroll
      for (int u = 0; u < 16; ++u) t0 += A[u] * W[u * 8 + w];
      float t1 = 0;
      #pragma unroll
      for (int jj = 0; jj < 3; ++jj) {
        float s1 = 0;
        #pragma unroll
        for (int u = 0; u < 6; ++u) s1 += A[16 + 3 * u + jj] * W[316 + 8 * u + w];
        t1 += s1 * b[1 + jj];
      }
      float t2 = 0;
      #pragma unroll
      for (int J = 0; J < 5; ++J) {
        float s2 = 0;
        #pragma unroll
        for (int u = 0; u < 4; ++u) s2 += A[34 + 5 * u + J] * W[472 + 8 * u + w];
        t2 += s2 * b[4 + J];
      }
      O0[w] += b[0] * t0 + I3 * t1 + I5 * t2;
    }

    // ---- O2 (3x3): paths (0,1,2), (2,0,2), (2,2,2), (3,1,2) ----
    #pragma unroll
    for (int w = 0; w < 3; ++w) {
      float ta = 0;
      #pragma unroll
      for (int u = 0; u < 16; ++u) ta += A[u] * W[128 + 3 * u + w];
      float tb[3], tc[3], td[5];
      #pragma unroll
      for (int k = 0; k < 3; ++k) {
        tb[k] = 0; tc[k] = 0;
        #pragma unroll
        for (int u = 0; u < 6; ++u) {
          tb[k] += A[16 + 3 * u + k] * W[298 + 3 * u + w];
          tc[k] += A[16 + 3 * u + k] * W[394 + 3 * u + w];
        }
      }
      #pragma unroll
      for (int I = 0; I < 5; ++I) {
        td[I] = 0;
        #pragma unroll
        for (int u = 0; u < 4; ++u) td[I] += A[34 + 5 * u + I] * W[444 + 3 * u + w];
      }
      O2[w * 3 + 0] += I3 * (b[1] * ta + b[0] * tb[0])
                     + tc[0] * c121_00 + tc[1] * c121_01 + tc[2] * c121_02
                     + td[0] * CBb1_2 + td[1] * CBb1_1 - td[2] * CAb1_0 - td[4] * CBb1_0;
      O2[w * 3 + 1] += I3 * (b[2] * ta + b[0] * tb[1])
                     + tc[0] * c121_01 + tc[1] * c121_11 + tc[2] * c121_12
                     + td[1] * CBb1_0 + td[2] * CCb1_1 + td[3] * CBb1_2;
      O2[w * 3 + 2] += I3 * (b[3] * ta + b[0] * tb[2])
                     + tc[0] * c121_02 + tc[1] * c121_12 + tc[2] * c121_22
                     + td[0] * CBb1_0 - td[2] * CAb1_2 + td[3] * CBb1_1 + td[4] * CBb1_2;
    }

    // ---- O3 (2x5): paths (0,2,3), (3,0,3), (2,1,3), (3,2,3) ----
    #pragma unroll
    for (int w = 0; w < 2; ++w) {
      float ta = 0;
      #pragma unroll
      for (int u = 0; u < 16; ++u) ta += A[u] * W[176 + 2 * u + w];
      float tb[5], td[5], tc[3];
      #pragma unroll
      for (int K = 0; K < 5; ++K) {
        tb[K] = 0; td[K] = 0;
        #pragma unroll
        for (int u = 0; u < 4; ++u) {
          tb[K] += A[34 + 5 * u + K] * W[436 + 2 * u + w];
          td[K] += A[34 + 5 * u + K] * W[516 + 2 * u + w];
        }
      }
      #pragma unroll
      for (int i = 0; i < 3; ++i) {
        tc[i] = 0;
        #pragma unroll
        for (int u = 0; u < 6; ++u) tc[i] += A[16 + 3 * u + i] * W[382 + 2 * u + w];
      }
      O3[w * 5 + 0] += I5 * (b[4] * ta + b[0] * tb[0])
                     + tc[0] * CBb1_2 + tc[2] * CBb1_0
                     - Pb2_2 * td[0] + Qb2_3 * td[1] - Pb2_0 * td[2] + Qb2_1 * td[3];
      O3[w * 5 + 1] += I5 * (b[5] * ta + b[0] * tb[1])
                     + tc[0] * CBb1_1 + tc[1] * CBb1_0
                     + Qb2_3 * td[0] + (Rb2_2 - Qb2_4) * td[1] + Rb2_1 * td[2] + Qb2_0 * td[3] - Qb2_1 * td[4];
      O3[w * 5 + 2] += I5 * (b[6] * ta + b[0] * tb[2])
                     - tc[0] * CAb1_0 + tc[1] * CCb1_1 - tc[2] * CAb1_2
                     - Pb2_0 * td[0] + Rb2_1 * td[1] + Pb2_2 * td[2] + Rb2_3 * td[3] - Pb2_4 * td[4];
      O3[w * 5 + 3] += I5 * (b[7] * ta + b[0] * tb[3])
                     + tc[1] * CBb1_2 + tc[2] * CBb1_1
                     + Qb2_1 * td[0] + Qb2_0 * td[1] + Rb2_3 * td[2] + (Rb2_2 + Qb2_4) * td[3] + Qb2_3 * td[4];
      O3[w * 5 + 4] += I5 * (b[8] * ta + b[0] * tb[4])
                     - tc[0] * CBb1_0 + tc[2] * CBb1_2
                     - Qb2_1 * td[1] - Pb2_4 * td[2] + Qb2_3 * td[3] - Pb2_2 * td[4];
    }
  }

  // scale -> nf2, then TP3 per-node precompute hh (9)
  const float S26 = 0.19611613513818404f, S14 = 0.2672612419124244f, S8 = 0.35355339059327373f;
  const float S13 = 0.2773500981126146f;
  float di = rsqrtf((float)cn);
  float F[27];
  #pragma unroll
  for (int w = 0; w < 8; ++w) F[w] = S26 * di * O0[w];
  #pragma unroll
  for (int i = 0; i < 9; ++i) F[8 + i] = S14 * di * O2[i];
  #pragma unroll
  for (int i = 0; i < 10; ++i) F[17 + i] = S8 * di * O3[i];

  float h[9];
  float t0 = 0;
  #pragma unroll
  for (int u = 0; u < 8; ++u) t0 += F[u] * w3[u];
  h[0] = S13 * t0;
  #pragma unroll
  for (int jj = 0; jj < 3; ++jj) {
    float s1 = 0;
    #pragma unroll
    for (int u = 0; u < 3; ++u) s1 += F[8 + 3 * u + jj] * w3[8 + u];
    h[1 + jj] = S13 * I3 * s1;
  }
  #pragma unroll
  for (int K = 0; K < 5; ++K)
    h[4 + K] = S13 * I5 * (F[17 + K] * w3[11] + F[22 + K] * w3[12]);

  float* o = hh + (size_t)n * 12;
  #pragma unroll
  for (int q = 0; q < 9; ++q) o[q] = h[q];
}

// ---------- layer 3 gather + molecule reduce ----------
__global__ void __launch_bounds__(64, 1)
k_gather3(const float* __restrict__ pos, const float* __restrict__ ea,
          const int* __restrict__ offs, const int* __restrict__ cnt,
          const int2* __restrict__ pairs, const float* __restrict__ hh,
          const int* __restrict__ batch, float* __restrict__ out) {
  int n = blockIdx.x * blockDim.x + threadIdx.x;
  if (n >= NNODES) return;
  int beg = offs[n], cn = cnt[n];
  float pdx = pos[3 * n], pdy = pos[3 * n + 1], pdz = pos[3 * n + 2];
  float v = 0.f;
  for (int j = 0; j < cn; ++j) {
    int2 pr = pairs[beg + j];
    int e = pr.x, s = pr.y;
    float w0 = ea[(size_t)e * 7];
    float dx = pos[3 * s] - pdx, dy = pos[3 * s + 1] - pdy, dz = pos[3 * s + 2] - pdz;
    float b[9]; make_b(w0, dx, dy, dz, b);
    float H[12];
    const float4* Hf = (const float4*)(hh + (size_t)s * 12);
    #pragma unroll
    for (int q = 0; q < 3; ++q) { float4 t = Hf[q]; H[4*q]=t.x; H[4*q+1]=t.y; H[4*q+2]=t.z; H[4*q+3]=t.w; }
    float d9 = 0;
    #pragma unroll
    for (int q = 0; q < 9; ++q) d9 += H[q] * b[q];
    v += d9;
  }
  float di = rsqrtf((float)cn);
  unsafeAtomicAdd(out + batch[n], v * di * 0.2f);  // /sqrt(apm)=/5
}

extern "C" void kernel_launch(void* const* d_in, const int* in_sizes, int n_in,
                              void* d_out, int out_size, void* d_ws, size_t ws_size,
                              hipStream_t stream) {
  const float* positions = (const float*)d_in[0];
  const float* x         = (const float*)d_in[1];
  const float* edge_attr = (const float*)d_in[2];
  const float* lin_w     = (const float*)d_in[3];
  const float* lin_b     = (const float*)d_in[4];
  const float* w_tp1     = (const float*)d_in[5];
  const float* w_tp2     = (const float*)d_in[6];
  const float* w_tp3     = (const float*)d_in[7];
  const int*   edge_src  = (const int*)d_in[8];
  const int*   edge_dst  = (const int*)d_in[9];
  const int*   batch     = (const int*)d_in[10];
  float* out = (float*)d_out;

  int*  cnt   = (int*)d_ws + OFF_CNT;
  int*  offs  = (int*)d_ws + OFF_OFFS;
  int*  curs  = (int*)d_ws + OFF_CURS;
  int*  bsum  = (int*)d_ws + OFF_BSUM;
  int2* pairs = (int2*)((int*)d_ws + OFF_PAIRS);
  float* g    = (float*)d_ws + OFF_G;
  float* nf1  = (float*)d_ws + OFF_NF1;
  float* hh   = (float*)d_ws + OFF_HH;

  hipMemsetAsync(cnt, 0, NNODES * sizeof(int), stream);
  hipMemsetAsync(out, 0, (size_t)out_size * sizeof(float), stream);

  dim3 blk256(256), blk64(64);
  dim3 gEdge((NEDGES + 255) / 256), gNode256((NNODES + 255) / 256), gNode64((NNODES + 63) / 64);

  k_count<<<gEdge, blk256, 0, stream>>>(edge_dst, cnt);
  k_scanA<<<dim3(NBLK), blk256, 0, stream>>>(cnt, offs, bsum);
  k_scanB<<<dim3(1), blk256, 0, stream>>>(bsum);
  k_scanC<<<dim3(NBLK), blk256, 0, stream>>>(offs, curs, bsum);
  k_fill<<<gEdge, blk256, 0, stream>>>(edge_src, edge_dst, curs, pairs);
  k_node1<<<gNode256, blk256, 0, stream>>>(x, lin_w, lin_b, w_tp1, g);
  k_gather1<<<gNode64, blk64, 0, stream>>>(positions, edge_attr, offs, cnt, pairs, g, nf1);
  k_gather2<<<gNode64, blk64, 0, stream>>>(positions, edge_attr, offs, cnt, pairs, nf1, w_tp2, w_tp3, hh);
  k_gather3<<<gNode64, blk64, 0, stream>>>(positions, edge_attr, offs, cnt, pairs, hh, batch, out);
}